// Round 2
// baseline (467.964 us; speedup 1.0000x reference)
//
#include <hip/hip_runtime.h>
#include <hip/hip_bf16.h>

#define NB    32      // batch
#define NCAP  2048    // input capsules
#define CL    1024    // C*L
#define ILEN  32

__device__ inline unsigned short f32_to_bf16_rne(float f) {
    unsigned int u = __float_as_uint(f);
    u += 0x7FFFu + ((u >> 16) & 1u);
    return (unsigned short)(u >> 16);
}

__device__ inline void unpack8(uint4 a, float* f) {
    f[0] = __uint_as_float(a.x << 16);
    f[1] = __uint_as_float(a.x & 0xFFFF0000u);
    f[2] = __uint_as_float(a.y << 16);
    f[3] = __uint_as_float(a.y & 0xFFFF0000u);
    f[4] = __uint_as_float(a.z << 16);
    f[5] = __uint_as_float(a.z & 0xFFFF0000u);
    f[6] = __uint_as_float(a.w << 16);
    f[7] = __uint_as_float(a.w & 0xFFFF0000u);
}

// ---------------------------------------------------------------------------
// Kernel A: u[b,j,k] = sum_i x[b,j,i] * W[j,i,k], stored bf16.
// v2: NO LDS staging of W, no per-tile barrier. Each lane streams its own
// float4 column of W directly from global (coalesced 1KB/wave/instr) with a
// depth-4 register prefetch ring. The 4x intra-block reuse of the W tile is
// served by L1/L2. LDS holds only the 4KB transposed x tile (broadcast reads),
// so occupancy is VGPR-limited (~7 blocks/CU) instead of LDS-limited (4),
// and ~100KB/CU of global loads stay in flight -> memory-bound streaming.
// Accumulation order (i ascending) identical to v1 -> bitwise-same results.
// ---------------------------------------------------------------------------
__global__ __launch_bounds__(256) void compute_u(const float* __restrict__ x,
                                                 const float* __restrict__ W,
                                                 unsigned short* __restrict__ u) {
    const int j  = blockIdx.x >> 2;
    const int kq = blockIdx.x & 3;
    const int t  = threadIdx.x;

    __shared__ float xs[32 * 32];    // [i][b]  (transposed)

    {
        int b  = t >> 3;
        int i4 = (t & 7) << 2;
        float4 v = *(const float4*)(x + ((size_t)b * NCAP + j) * ILEN + i4);
        xs[(i4 + 0) * 32 + b] = v.x;
        xs[(i4 + 1) * 32 + b] = v.y;
        xs[(i4 + 2) * 32 + b] = v.z;
        xs[(i4 + 3) * 32 + b] = v.w;
    }
    __syncthreads();

    const int lane = t & 63;   // k chunk within slice
    const int wv   = t >> 6;   // b-octet

    // each lane owns 4 consecutive k columns; reads W rows i=0..31 directly
    const float* Wp = W + (size_t)j * (ILEN * CL) + kq * 256 + (lane << 2);

    float acc[8][4];
#pragma unroll
    for (int bb = 0; bb < 8; ++bb)
#pragma unroll
        for (int q = 0; q < 4; ++q) acc[bb][q] = 0.f;

    // depth-4 prefetch ring on the W stream
    float4 wbuf[4];
#pragma unroll
    for (int p = 0; p < 4; ++p) wbuf[p] = *(const float4*)(Wp + (size_t)p * CL);

#pragma unroll
    for (int i = 0; i < 32; ++i) {
        float4 w4 = wbuf[i & 3];
        if (i + 4 < 32) wbuf[i & 3] = *(const float4*)(Wp + (size_t)(i + 4) * CL);
        float4 xa = *(const float4*)(xs + i * 32 + wv * 8);       // broadcast
        float4 xb = *(const float4*)(xs + i * 32 + wv * 8 + 4);   // broadcast
        float xv[8] = {xa.x, xa.y, xa.z, xa.w, xb.x, xb.y, xb.z, xb.w};
#pragma unroll
        for (int bb = 0; bb < 8; ++bb) {
            acc[bb][0] += xv[bb] * w4.x;
            acc[bb][1] += xv[bb] * w4.y;
            acc[bb][2] += xv[bb] * w4.z;
            acc[bb][3] += xv[bb] * w4.w;
        }
    }

    const int k = kq * 256 + (lane << 2);
#pragma unroll
    for (int bb = 0; bb < 8; ++bb) {
        int b = wv * 8 + bb;
        ushort4 o;
        o.x = f32_to_bf16_rne(acc[bb][0]);
        o.y = f32_to_bf16_rne(acc[bb][1]);
        o.z = f32_to_bf16_rne(acc[bb][2]);
        o.w = f32_to_bf16_rne(acc[bb][3]);
        *(ushort4*)(u + ((size_t)b * NCAP + j) * CL + k) = o;
    }
}

// ---------------------------------------------------------------------------
// Routing pass, barrier-free inner loop. Lane i owns c0 = i>>2 (l = (i&3)*8..+8)
// and c1 = c0+16. Softmax over C done entirely with shfl_xor; every wave does
// its own softmax (no idle waves). Depth-2 prefetch. Block writes an
// atomic-free partial s to spart[b][jc][1024].
// ---------------------------------------------------------------------------
template<bool HAS_V>
__global__ __launch_bounds__(256) void route_pass(const unsigned short* __restrict__ u,
                                                  const float* __restrict__ vlog,
                                                  float* __restrict__ spart) {
    const int b    = blockIdx.x;
    const int jc   = blockIdx.y;
    const int t    = threadIdx.x;
    const int wv   = t >> 6;
    const int lane = t & 63;
    const int c0   = lane >> 2;           // 0..15
    const int sub  = lane & 3;
    const int e0   = c0 * 32 + sub * 8;   // element offset of fragment 0
    // fragment 1 lives at e0 + 512 (capsule c0+16)

    float vme0[8], vme1[8];
    if (HAS_V) {
        const float* vb = vlog + b * CL;
        *(float4*)(vme0)     = *(const float4*)(vb + e0);
        *(float4*)(vme0 + 4) = *(const float4*)(vb + e0 + 4);
        *(float4*)(vme1)     = *(const float4*)(vb + e0 + 512);
        *(float4*)(vme1 + 4) = *(const float4*)(vb + e0 + 516);
    }

    const int jbase = jc * 128 + wv * 32;
    const unsigned short* ub = u + ((size_t)b * NCAP + jbase) * CL;

    float acc0[8], acc1[8];
#pragma unroll
    for (int e = 0; e < 8; ++e) { acc0[e] = 0.f; acc1[e] = 0.f; }

    // depth-2 software pipeline
    uint4 a0 = *(const uint4*)(ub + 0 * CL + e0);
    uint4 g0 = *(const uint4*)(ub + 0 * CL + e0 + 512);
    uint4 a1 = *(const uint4*)(ub + 1 * CL + e0);
    uint4 g1 = *(const uint4*)(ub + 1 * CL + e0 + 512);

    for (int jj = 0; jj < 32; ++jj) {
        int jn = (jj + 2 < 32) ? (jj + 2) : 31;
        uint4 a2 = *(const uint4*)(ub + (size_t)jn * CL + e0);
        uint4 g2 = *(const uint4*)(ub + (size_t)jn * CL + e0 + 512);

        float uf0[8], uf1[8];
        unpack8(a0, uf0);
        unpack8(g0, uf1);

        float cw0, cw1;
        if (HAS_V) {
            float p0 = 0.f, p1 = 0.f;
#pragma unroll
            for (int e = 0; e < 8; ++e) { p0 += uf0[e] * vme0[e]; p1 += uf1[e] * vme1[e]; }
            p0 += __shfl_xor(p0, 1); p0 += __shfl_xor(p0, 2);
            p1 += __shfl_xor(p1, 1); p1 += __shfl_xor(p1, 2);
            float m = fmaxf(p0, p1);
            m = fmaxf(m, __shfl_xor(m, 4));
            m = fmaxf(m, __shfl_xor(m, 8));
            m = fmaxf(m, __shfl_xor(m, 16));
            m = fmaxf(m, __shfl_xor(m, 32));
            float ex0 = __expf(p0 - m);
            float ex1 = __expf(p1 - m);
            float ssum = ex0 + ex1;
            ssum += __shfl_xor(ssum, 4);
            ssum += __shfl_xor(ssum, 8);
            ssum += __shfl_xor(ssum, 16);
            ssum += __shfl_xor(ssum, 32);
            float inv = __builtin_amdgcn_rcpf(ssum);
            cw0 = ex0 * inv;
            cw1 = ex1 * inv;
        } else {
            cw0 = 0.03125f;
            cw1 = 0.03125f;
        }
#pragma unroll
        for (int e = 0; e < 8; ++e) {
            acc0[e] += cw0 * uf0[e];
            acc1[e] += cw1 * uf1[e];
        }
        a0 = a1; g0 = g1; a1 = a2; g1 = g2;
    }

    // block reduction (no atomics): 4 waves -> one partial vector
    __shared__ float red[4][1024];
    *(float4*)(&red[wv][e0])       = *(float4*)(acc0);
    *(float4*)(&red[wv][e0 + 4])   = *(float4*)(acc0 + 4);
    *(float4*)(&red[wv][e0 + 512]) = *(float4*)(acc1);
    *(float4*)(&red[wv][e0 + 516]) = *(float4*)(acc1 + 4);
    __syncthreads();

    const int o = t * 4;
    float4 r0 = *(float4*)(&red[0][o]);
    float4 r1 = *(float4*)(&red[1][o]);
    float4 r2 = *(float4*)(&red[2][o]);
    float4 r3 = *(float4*)(&red[3][o]);
    float4 r;
    r.x = (r0.x + r1.x) + (r2.x + r3.x);
    r.y = (r0.y + r1.y) + (r2.y + r3.y);
    r.z = (r0.z + r1.z) + (r2.z + r3.z);
    r.w = (r0.w + r1.w) + (r2.w + r3.w);
    *(float4*)(spart + ((size_t)b * 16 + jc) * CL + o) = r;
}

// ---------------------------------------------------------------------------
// Squash: sums the 16 per-jc partials, adds biases, squashes.
// Optionally emits vlog_out = v + vprev (cumulative logit v).
// ---------------------------------------------------------------------------
__global__ __launch_bounds__(256) void squash_kernel(const float* __restrict__ spart,
                                                     const float* __restrict__ biases,
                                                     float* __restrict__ vout,
                                                     float* __restrict__ vlog_out,
                                                     const float* __restrict__ vprev) {
    const int b = blockIdx.x;
    const int t = threadIdx.x;

    float4 sv = make_float4(0.f, 0.f, 0.f, 0.f);
#pragma unroll
    for (int p = 0; p < 16; ++p) {
        float4 q = *(const float4*)(spart + ((size_t)b * 16 + p) * CL + t * 4);
        sv.x += q.x; sv.y += q.y; sv.z += q.z; sv.w += q.w;
    }
    float4 bi = *(const float4*)(biases + t * 4);
    sv.x += bi.x; sv.y += bi.y; sv.z += bi.z; sv.w += bi.w;

    float n2 = sv.x * sv.x + sv.y * sv.y + sv.z * sv.z + sv.w * sv.w;
    n2 += __shfl_xor(n2, 1);
    n2 += __shfl_xor(n2, 2);
    n2 += __shfl_xor(n2, 4);

    float n = sqrtf(n2);
    float f = n2 / ((1.f + n2) * (n + 1e-7f));

    float4 v;
    v.x = f * sv.x; v.y = f * sv.y; v.z = f * sv.z; v.w = f * sv.w;
    *(float4*)(vout + b * CL + t * 4) = v;

    if (vlog_out != nullptr) {
        float4 a = make_float4(0.f, 0.f, 0.f, 0.f);
        if (vprev != nullptr) a = *(const float4*)(vprev + b * CL + t * 4);
        float4 o;
        o.x = v.x + a.x; o.y = v.y + a.y; o.z = v.z + a.z; o.w = v.w + a.w;
        *(float4*)(vlog_out + b * CL + t * 4) = o;
    }
}

// ---------------------------------------------------------------------------
extern "C" void kernel_launch(void* const* d_in, const int* in_sizes, int n_in,
                              void* d_out, int out_size, void* d_ws, size_t ws_size,
                              hipStream_t stream) {
    const float* x      = (const float*)d_in[0];   // (32, 2048, 32)
    const float* W      = (const float*)d_in[1];   // (2048, 32, 1024)
    const float* biases = (const float*)d_in[2];   // (32, 32)
    float* out = (float*)d_out;                    // (32, 32, 32)

    unsigned short* u = (unsigned short*)d_ws;                     // 128 MB bf16
    float* fb    = (float*)((char*)d_ws + (size_t)NB * NCAP * CL * 2);
    float* spart = fb;                  // 32*16*1024 = 524288 floats
    float* v0    = spart + 524288;
    float* vl2   = v0 + 32768;
    float* vdmp  = vl2 + 32768;

    compute_u<<<NCAP * 4, 256, 0, stream>>>(x, W, u);

    dim3 rg(NB, 16);
    // r = 0: zero logits -> coupling exactly 1/32, no softmax needed
    route_pass<false><<<rg, 256, 0, stream>>>(u, nullptr, spart);
    squash_kernel<<<NB, 256, 0, stream>>>(spart, biases, v0, nullptr, nullptr);
    // r = 1: logits = u . v0
    route_pass<true><<<rg, 256, 0, stream>>>(u, v0, spart);
    squash_kernel<<<NB, 256, 0, stream>>>(spart, biases, vdmp, vl2, v0);
    // r = 2: logits = u . (v0 + v1)
    route_pass<true><<<rg, 256, 0, stream>>>(u, vl2, spart);
    squash_kernel<<<NB, 256, 0, stream>>>(spart, biases, out, nullptr, nullptr);
}